// Round 12
// baseline (205.393 us; speedup 1.0000x reference)
//
#include <hip/hip_runtime.h>
#include <hip/hip_bf16.h>
#include <stdint.h>

#define BATCH 4096
#define TLEN  1024
#define MSTR  72     // LDS stride (bf16 elems) for T matrices; 144B keeps b64/b128 alignment
#define CSTR  68     // combine buffer stride (f32); 272B keeps f32x4 alignment

// ---- LDS layout (bytes) ----
#define OFF_T    0        // Tsm plain [64][MSTR] bf16   (bwd A source)
#define OFF_G    9216     // Tsm^T     [64][MSTR] bf16   (fwd A source)
#define OFF_PE   18432    // float pE[2][64]
#define OFF_PIV  18944    // float piv[64]
#define OFF_YB   19200    // u64 yball[16][16] = 2048
#define OFF_CMB  21376    // float gamma[16][CSTR]
#define OFF_LACB 25728    // float laccB[16]
#define OFF_YS   25792    // u64 ybsL[2 waves][8 words][64 lanes] = 8192
#define SMEM_SZ  33984

typedef short        bf16x4 __attribute__((ext_vector_type(4)));
typedef short        bf16x8 __attribute__((ext_vector_type(8)));
typedef float        f32x4  __attribute__((ext_vector_type(4)));
typedef unsigned int u32;
typedef unsigned int u32x4  __attribute__((ext_vector_type(4)));

#define MFMA(a,b,c) __builtin_amdgcn_mfma_f32_16x16x32_bf16(a,b,c,0,0,0)

// Hardware packed f32->2xbf16 (RNE), proven in round 7.
static __device__ __forceinline__ u32 packpair(float lo, float hi) {
    u32 r;
    asm("v_cvt_pk_bf16_f32 %0, %1, %2" : "=&v"(r) : "v"(lo), "v"(hi));
    return r;
}

// ---------------------------------------------------------------------------
// 256 wgs x 128 thr (2 waves). wg = 16-batch block, BOTH directions:
//   wave0: forward  alpha-chain, A = T^T (permuted k-order)
//   wave1: backward gamma-chain (gamma_t = e_t ⊙ beta_t), A = T (permuted)
// ROUND-12 DELTA vs round 7 (the only change): SPLIT-K accumulators.
// r6->r7->r11 showed cy/step converging on a ~570-cy instruction-count-
// independent floor — a LATENCY floor. r7's step carries TWO sequential
// MFMA result-latencies (K=64 as two C-chained K=32 MFMAs). Here the two
// K-halves go into INDEPENDENT accumulators (both C=0, latencies overlap)
// combined with 8 vector f32 adds: serial path loses one full MFMA latency
// at the cost of +16 scalar adds. Everything else byte-identical round 7:
// cvt_pk pack, sigma-permuted register chain, per-lane LDS bit-words,
// code-size-bounded 31x16+15 loop, renorm every 16 steps, combine in-wg.
// ---------------------------------------------------------------------------
__global__ __launch_bounds__(128, 1) void hmm_fb(
    const int* __restrict__ y, const float* __restrict__ Tmat,
    const float* __restrict__ Emat, const float* __restrict__ Pi,
    float* __restrict__ out)
{
    __shared__ __align__(16) unsigned char SM[SMEM_SZ];

    const int tid  = threadIdx.x;
    const int wv   = tid >> 6;          // 0 = fwd, 1 = bwd
    const int lane = tid & 63;
    const int lr   = lane & 15;         // batch col
    const int g    = lane >> 4;         // k-group
    const int R0   = blockIdx.x << 4;

    float* pE  = (float*)(SM + OFF_PE);
    float* piv = (float*)(SM + OFF_PIV);
    const f32x4 zero = {0.f, 0.f, 0.f, 0.f};

    // ---- phase 0: emission + pi softmax ----
    if (tid < 64) {
        const float e0 = Emat[tid*2+0], e1 = Emat[tid*2+1];
        const float em = fmaxf(e0, e1);
        const float p0 = __expf(e0-em), p1 = __expf(e1-em);
        const float ez = 1.0f / (p0 + p1);
        pE[tid]      = p0 * ez;
        pE[64 + tid] = p1 * ez;
        float v = Pi[tid];
        float mx = v;
        #pragma unroll
        for (int d = 1; d < 64; d <<= 1) mx = fmaxf(mx, __shfl_xor(mx, d));
        const float e = __expf(v - mx);
        float z = e;
        #pragma unroll
        for (int d = 1; d < 64; d <<= 1) z += __shfl_xor(z, d);
        piv[tid] = e / z;
    }

    // ---- phase 1: row-softmax of T -> plain + transposed bf16 ----
    {
        const int r  = tid >> 1;          // 0..63
        const int hh = tid & 1;           // 32-col half
        float v[32];
        #pragma unroll
        for (int q = 0; q < 8; q++) {
            const float4 t4 = *(const float4*)(Tmat + r*64 + hh*32 + q*4);
            v[q*4+0]=t4.x; v[q*4+1]=t4.y; v[q*4+2]=t4.z; v[q*4+3]=t4.w;
        }
        float mx = v[0];
        #pragma unroll
        for (int k = 1; k < 32; k++) mx = fmaxf(mx, v[k]);
        mx = fmaxf(mx, __shfl_xor(mx, 1));
        float z = 0.f;
        #pragma unroll
        for (int k = 0; k < 32; k++) { v[k] = __expf(v[k]-mx); z += v[k]; }
        z += __shfl_xor(z, 1);
        const float inv = 1.0f / z;
        __hip_bfloat16* Tsm = (__hip_bfloat16*)(SM + OFF_T);
        __hip_bfloat16* Gt  = (__hip_bfloat16*)(SM + OFF_G);
        #pragma unroll
        for (int k = 0; k < 32; k++) {
            const int j = hh*32 + k;
            const __hip_bfloat16 hb = __float2bfloat16(v[k] * inv);
            Tsm[r*MSTR + j] = hb;     // Tsm[s][s']
            Gt[j*MSTR + r]  = hb;     // Gt[s'][s] = T[s][s']
        }
    }
    __syncthreads();

    // ---- phase 2: gather permuted A-fragments (register-resident) ----
    // A[m][h] element j (lane g): col sigma = 32h + 4g + (j&3) + 16*(j>>2)
    bf16x8 A00,A01,A10,A11,A20,A21,A30,A31;
    {
        const __hip_bfloat16* Abase =
            (const __hip_bfloat16*)(SM + (wv == 0 ? OFF_G : OFF_T));
        #define LDFRAG(dst, m, h) { \
            const __hip_bfloat16* p_ = Abase + ((m)*16+lr)*MSTR + 32*(h) + 4*g; \
            bf16x4 lo_ = *(const bf16x4*)(p_); \
            bf16x4 hi_ = *(const bf16x4*)(p_ + 16); \
            dst[0]=lo_[0]; dst[1]=lo_[1]; dst[2]=lo_[2]; dst[3]=lo_[3]; \
            dst[4]=hi_[0]; dst[5]=hi_[1]; dst[6]=hi_[2]; dst[7]=hi_[3]; \
        }
        LDFRAG(A00,0,0); LDFRAG(A01,0,1); LDFRAG(A10,1,0); LDFRAG(A11,1,1);
        LDFRAG(A20,2,0); LDFRAG(A21,2,1); LDFRAG(A30,3,0); LDFRAG(A31,3,1);
        #undef LDFRAG
    }

    // ---- phase 3: ballot-pack y into LDS words ----
    unsigned long long* yball = (unsigned long long*)(SM + OFF_YB);
    #pragma unroll
    for (int q = 0; q < 8; q++) {
        const int row = wv*8 + q;
        const int* yr = y + (size_t)(R0 + row) * TLEN;
        #pragma unroll
        for (int w = 0; w < 16; w++) {
            const unsigned long long bal = __ballot(yr[w*64 + lane] != 0);
            if (lane == 0) yball[row*16 + w] = bal;
        }
    }
    __syncthreads();

    // ---- phase 4: per-lane bit-streams -> per-lane LDS slots ----
    // stream bit s: fwd -> y[s+1] (s=0..510); bwd -> y[1022-s]
    unsigned long long* ybsL = (unsigned long long*)(SM + OFF_YS) + wv*(8*64);
    int initbit;
    {
        unsigned long long raw[8];
        if (wv == 0) {
            #pragma unroll
            for (int w = 0; w < 8; w++) raw[w] = yball[lr*16 + w];
        } else {
            #pragma unroll
            for (int w = 0; w < 8; w++) raw[w] = __brevll(yball[lr*16 + (15-w)]);
        }
        initbit = (int)(raw[0] & 1ull);           // fwd: y[0]; bwd: y[1023]
        #pragma unroll
        for (int w = 0; w < 7; w++)
            ybsL[w*64 + lane] = (raw[w] >> 1) | (raw[w+1] << 63);
        ybsL[7*64 + lane] = raw[7] >> 1;
    }
    // Each lane reads back ONLY its own ybsL slots (same-wave write->read).

    const f32x4 e0_0 = *(const f32x4*)(pE +       0 + 4*g);
    const f32x4 e0_1 = *(const f32x4*)(pE +      16 + 4*g);
    const f32x4 e0_2 = *(const f32x4*)(pE +      32 + 4*g);
    const f32x4 e0_3 = *(const f32x4*)(pE +      48 + 4*g);
    const f32x4 e1_0 = *(const f32x4*)(pE + 64 +  0 + 4*g);
    const f32x4 e1_1 = *(const f32x4*)(pE + 64 + 16 + 4*g);
    const f32x4 e1_2 = *(const f32x4*)(pE + 64 + 32 + 4*g);
    const f32x4 e1_3 = *(const f32x4*)(pE + 64 + 48 + 4*g);

    f32x4 d0, d1, d2, d3;
    if (wv == 0) {                        // alpha_0 = piv ⊙ e_{y0}
        const f32x4 p0 = *(const f32x4*)(piv +  0 + 4*g);
        const f32x4 p1 = *(const f32x4*)(piv + 16 + 4*g);
        const f32x4 p2 = *(const f32x4*)(piv + 32 + 4*g);
        const f32x4 p3 = *(const f32x4*)(piv + 48 + 4*g);
        d0 = p0 * (initbit ? e1_0 : e0_0);
        d1 = p1 * (initbit ? e1_1 : e0_1);
        d2 = p2 * (initbit ? e1_2 : e0_2);
        d3 = p3 * (initbit ? e1_3 : e0_3);
    } else {                              // gamma_1023 = e_{y1023}
        d0 = initbit ? e1_0 : e0_0;
        d1 = initbit ? e1_1 : e0_1;
        d2 = initbit ? e1_2 : e0_2;
        d3 = initbit ? e1_3 : e0_3;
    }

    // ---- main loop: 511 register-only steps, split-K accumulators ----
    f32x4 t0, t1, t2, t3;
    #define DO_MM() { \
        u32x4 w1_, w2_; \
        w1_[0] = packpair(d0.x, d0.y);  w1_[1] = packpair(d0.z, d0.w); \
        w1_[2] = packpair(d1.x, d1.y);  w1_[3] = packpair(d1.z, d1.w); \
        w2_[0] = packpair(d2.x, d2.y);  w2_[1] = packpair(d2.z, d2.w); \
        w2_[2] = packpair(d3.x, d3.y);  w2_[3] = packpair(d3.z, d3.w); \
        const bf16x8 b1 = __builtin_bit_cast(bf16x8, w1_); \
        const bf16x8 b2 = __builtin_bit_cast(bf16x8, w2_); \
        const f32x4 u0_ = MFMA(A00, b1, zero); \
        const f32x4 u1_ = MFMA(A10, b1, zero); \
        const f32x4 u2_ = MFMA(A20, b1, zero); \
        const f32x4 u3_ = MFMA(A30, b1, zero); \
        const f32x4 v0_ = MFMA(A01, b2, zero); \
        const f32x4 v1_ = MFMA(A11, b2, zero); \
        const f32x4 v2_ = MFMA(A21, b2, zero); \
        const f32x4 v3_ = MFMA(A31, b2, zero); \
        t0 = u0_ + v0_;  t1 = u1_ + v1_; \
        t2 = u2_ + v2_;  t3 = u3_ + v3_; \
    }
    #define EMIT_BIT(cond) { \
        const bool yb_ = (cond); \
        d0 = t0 * (yb_ ? e1_0 : e0_0); \
        d1 = t1 * (yb_ ? e1_1 : e0_1); \
        d2 = t2 * (yb_ ? e1_2 : e0_2); \
        d3 = t3 * (yb_ ? e1_3 : e0_3); \
    }

    float lacc = 0.f;
    // 31 groups x 16 steps = steps 0..495; renorm at step 15 of each group.
    #pragma unroll 1
    for (int grp = 0; grp < 31; ++grp) {
        const unsigned long long cw = ybsL[((grp >> 2) << 6) + lane];
        const u32 bits = (u32)(cw >> ((grp & 3) << 4));
        #pragma unroll
        for (int i = 0; i < 16; ++i) {
            DO_MM();
            if (i == 15) {                      // renorm every 16 steps
                float S = t0.x+t0.y+t0.z+t0.w + t1.x+t1.y+t1.z+t1.w
                        + t2.x+t2.y+t2.z+t2.w + t3.x+t3.y+t3.z+t3.w;
                S += __shfl_xor(S, 16);
                S += __shfl_xor(S, 32);
                lacc += __logf(S);
                const float rn = __builtin_amdgcn_rcpf(S);
                t0 *= rn; t1 *= rn; t2 *= rn; t3 *= rn;
            }
            EMIT_BIT(((bits >> i) & 1u) != 0u);
        }
    }
    // tail: steps 496..510 (stream bits 48..62 of word 7), rolled
    {
        u32 bits = (u32)(ybsL[(7 << 6) + lane] >> 48);
        #pragma unroll 1
        for (int i = 0; i < 15; ++i) {
            DO_MM();
            EMIT_BIT((bits & 1u) != 0u);
            bits >>= 1;
        }
    }

    // ---- fwd: one bare matvec (no emission) -> abar_512 ----
    if (wv == 0) {
        DO_MM();
        d0 = t0; d1 = t1; d2 = t2; d3 = t3;
    }
    #undef DO_MM
    #undef EMIT_BIT

    // ---- combine: logP = laccF + laccB + log(abar_512 . gamma_512) ----
    if (wv == 1) {
        float* CB = (float*)(SM + OFF_CMB);
        *(f32x4*)(CB + lr*CSTR +  0 + 4*g) = d0;
        *(f32x4*)(CB + lr*CSTR + 16 + 4*g) = d1;
        *(f32x4*)(CB + lr*CSTR + 32 + 4*g) = d2;
        *(f32x4*)(CB + lr*CSTR + 48 + 4*g) = d3;
        if (lane < 16) ((float*)(SM + OFF_LACB))[lane] = lacc;
    }
    __syncthreads();
    if (wv == 0) {
        const float* CB = (const float*)(SM + OFF_CMB);
        const f32x4 q0 = *(const f32x4*)(CB + lr*CSTR +  0 + 4*g);
        const f32x4 q1 = *(const f32x4*)(CB + lr*CSTR + 16 + 4*g);
        const f32x4 q2 = *(const f32x4*)(CB + lr*CSTR + 32 + 4*g);
        const f32x4 q3 = *(const f32x4*)(CB + lr*CSTR + 48 + 4*g);
        float dot = d0.x*q0.x + d0.y*q0.y + d0.z*q0.z + d0.w*q0.w
                  + d1.x*q1.x + d1.y*q1.y + d1.z*q1.z + d1.w*q1.w
                  + d2.x*q2.x + d2.y*q2.y + d2.z*q2.z + d2.w*q2.w
                  + d3.x*q3.x + d3.y*q3.y + d3.z*q3.z + d3.w*q3.w;
        dot += __shfl_xor(dot, 16);
        dot += __shfl_xor(dot, 32);
        float lp = lacc + ((const float*)(SM + OFF_LACB))[lr] + __logf(dot);
        if (g == 0) {                      // lanes 0..15: reduce over batch
            lp += __shfl_xor(lp, 1);
            lp += __shfl_xor(lp, 2);
            lp += __shfl_xor(lp, 4);
            lp += __shfl_xor(lp, 8);
            if (lr == 0) atomicAdd(out, lp * (1.0f / BATCH));
        }
    }
}

// ---------------------------------------------------------------------------
extern "C" void kernel_launch(void* const* d_in, const int* in_sizes, int n_in,
                              void* d_out, int out_size, void* d_ws, size_t ws_size,
                              hipStream_t stream) {
    const int*   y  = (const int*)  d_in[0];
    const float* T  = (const float*)d_in[1];
    const float* E  = (const float*)d_in[2];
    const float* Pi = (const float*)d_in[3];
    float* out = (float*)d_out;
    (void)d_ws; (void)ws_size; (void)in_sizes; (void)n_in; (void)out_size;

    hipMemsetAsync(out, 0, sizeof(float), stream);
    hipLaunchKernelGGL(hmm_fb, dim3(BATCH/16), dim3(128), 0, stream,
                       y, T, E, Pi, out);
}

// Round 13
// 175.352 us; speedup vs baseline: 1.1713x; 1.1713x over previous
//
#include <hip/hip_runtime.h>
#include <hip/hip_bf16.h>
#include <stdint.h>

#define BATCH 4096
#define TLEN  1024
#define MSTR  72     // LDS stride (bf16 elems) for T matrices; 144B keeps b64/b128 alignment
#define CSTR  68     // combine buffer stride (f32); 272B keeps f32x4 alignment

// ---- LDS layout (bytes) ----
#define OFF_T    0        // Tsm plain [64][MSTR] bf16   (bwd A source)
#define OFF_G    9216     // Tsm^T     [64][MSTR] bf16   (fwd A source)
#define OFF_PE   18432    // float pE[2][64]
#define OFF_PIV  18944    // float piv[64]
#define OFF_YB   19200    // u64 yball[16][16] = 2048
#define OFF_CMB  21376    // float gamma[16][CSTR]
#define OFF_LACB 25728    // float laccB[16]
#define OFF_YS   25792    // u64 ybsL[2 waves][8 words][64 lanes] = 8192
#define SMEM_SZ  33984

typedef short        bf16x4 __attribute__((ext_vector_type(4)));
typedef short        bf16x8 __attribute__((ext_vector_type(8)));
typedef float        f32x2  __attribute__((ext_vector_type(2)));
typedef float        f32x4  __attribute__((ext_vector_type(4)));
typedef unsigned int u32;
typedef unsigned int u32x4  __attribute__((ext_vector_type(4)));

#define MFMA(a,b,c) __builtin_amdgcn_mfma_f32_16x16x32_bf16(a,b,c,0,0,0)

// Hardware packed f32->2xbf16 (RNE), proven in round 7.
static __device__ __forceinline__ u32 packpair(float lo, float hi) {
    u32 r;
    asm("v_cvt_pk_bf16_f32 %0, %1, %2" : "=&v"(r) : "v"(lo), "v"(hi));
    return r;
}
// ROUND-13 DELTA: packed fp32 math (VOP3P, full-rate on CDNA) for EMIT.
// 2 f32 per instruction on register pairs.
static __device__ __forceinline__ f32x2 pk_fma(f32x2 a, f32x2 b, f32x2 c) {
    f32x2 d;
    asm("v_pk_fma_f32 %0, %1, %2, %3" : "=v"(d) : "v"(a), "v"(b), "v"(c));
    return d;
}
static __device__ __forceinline__ f32x2 pk_mul(f32x2 a, f32x2 b) {
    f32x2 d;
    asm("v_pk_mul_f32 %0, %1, %2" : "=v"(d) : "v"(a), "v"(b));
    return d;
}
// Sub-register pair halves of an MFMA output quad (even-aligned -> free).
static __device__ __forceinline__ f32x2 lo2(f32x4 v) { return __builtin_shufflevector(v, v, 0, 1); }
static __device__ __forceinline__ f32x2 hi2(f32x4 v) { return __builtin_shufflevector(v, v, 2, 3); }

// ---------------------------------------------------------------------------
// 256 wgs x 128 thr (2 waves). wg = 16-batch block, BOTH directions:
//   wave0: forward  alpha-chain, A = T^T (permuted k-order)
//   wave1: backward gamma-chain (gamma_t = e_t ⊙ beta_t), A = T (permuted)
// ROUND-13 vs round 7 (best, 124us dispatch): EMIT rewritten in packed
// fp32 — e_sel = pk_fma(bitf2, e1-e0, e0); d = pk_mul(t_half, e_sel).
// 18 ops vs 32 (r6..r12 ledger: lone-wave time ≈ instrs × ~10cy, so
// -14 instr/step predicts ~-140cy/step). d-state is 8 f32x2 pairs (feeds
// cvt_pk directly). Everything else byte-identical round 7: cvt_pk pack,
// sigma-permuted register chain (C-chained MFMA — r12 proved split-K is
// worse), per-lane LDS bit-words, 31x16+15 code-size-bounded loop,
// renorm every 16 steps, combine in-wg.
// ---------------------------------------------------------------------------
__global__ __launch_bounds__(128, 1) void hmm_fb(
    const int* __restrict__ y, const float* __restrict__ Tmat,
    const float* __restrict__ Emat, const float* __restrict__ Pi,
    float* __restrict__ out)
{
    __shared__ __align__(16) unsigned char SM[SMEM_SZ];

    const int tid  = threadIdx.x;
    const int wv   = tid >> 6;          // 0 = fwd, 1 = bwd
    const int lane = tid & 63;
    const int lr   = lane & 15;         // batch col
    const int g    = lane >> 4;         // k-group
    const int R0   = blockIdx.x << 4;

    float* pE  = (float*)(SM + OFF_PE);
    float* piv = (float*)(SM + OFF_PIV);
    const f32x4 zero = {0.f, 0.f, 0.f, 0.f};

    // ---- phase 0: emission + pi softmax ----
    if (tid < 64) {
        const float e0 = Emat[tid*2+0], e1 = Emat[tid*2+1];
        const float em = fmaxf(e0, e1);
        const float p0 = __expf(e0-em), p1 = __expf(e1-em);
        const float ez = 1.0f / (p0 + p1);
        pE[tid]      = p0 * ez;
        pE[64 + tid] = p1 * ez;
        float v = Pi[tid];
        float mx = v;
        #pragma unroll
        for (int d = 1; d < 64; d <<= 1) mx = fmaxf(mx, __shfl_xor(mx, d));
        const float e = __expf(v - mx);
        float z = e;
        #pragma unroll
        for (int d = 1; d < 64; d <<= 1) z += __shfl_xor(z, d);
        piv[tid] = e / z;
    }

    // ---- phase 1: row-softmax of T -> plain + transposed bf16 ----
    {
        const int r  = tid >> 1;          // 0..63
        const int hh = tid & 1;           // 32-col half
        float v[32];
        #pragma unroll
        for (int q = 0; q < 8; q++) {
            const float4 t4 = *(const float4*)(Tmat + r*64 + hh*32 + q*4);
            v[q*4+0]=t4.x; v[q*4+1]=t4.y; v[q*4+2]=t4.z; v[q*4+3]=t4.w;
        }
        float mx = v[0];
        #pragma unroll
        for (int k = 1; k < 32; k++) mx = fmaxf(mx, v[k]);
        mx = fmaxf(mx, __shfl_xor(mx, 1));
        float z = 0.f;
        #pragma unroll
        for (int k = 0; k < 32; k++) { v[k] = __expf(v[k]-mx); z += v[k]; }
        z += __shfl_xor(z, 1);
        const float inv = 1.0f / z;
        __hip_bfloat16* Tsm = (__hip_bfloat16*)(SM + OFF_T);
        __hip_bfloat16* Gt  = (__hip_bfloat16*)(SM + OFF_G);
        #pragma unroll
        for (int k = 0; k < 32; k++) {
            const int j = hh*32 + k;
            const __hip_bfloat16 hb = __float2bfloat16(v[k] * inv);
            Tsm[r*MSTR + j] = hb;     // Tsm[s][s']
            Gt[j*MSTR + r]  = hb;     // Gt[s'][s] = T[s][s']
        }
    }
    __syncthreads();

    // ---- phase 2: gather permuted A-fragments (register-resident) ----
    // A[m][h] element j (lane g): col sigma = 32h + 4g + (j&3) + 16*(j>>2)
    bf16x8 A00,A01,A10,A11,A20,A21,A30,A31;
    {
        const __hip_bfloat16* Abase =
            (const __hip_bfloat16*)(SM + (wv == 0 ? OFF_G : OFF_T));
        #define LDFRAG(dst, m, h) { \
            const __hip_bfloat16* p_ = Abase + ((m)*16+lr)*MSTR + 32*(h) + 4*g; \
            bf16x4 lo_ = *(const bf16x4*)(p_); \
            bf16x4 hi_ = *(const bf16x4*)(p_ + 16); \
            dst[0]=lo_[0]; dst[1]=lo_[1]; dst[2]=lo_[2]; dst[3]=lo_[3]; \
            dst[4]=hi_[0]; dst[5]=hi_[1]; dst[6]=hi_[2]; dst[7]=hi_[3]; \
        }
        LDFRAG(A00,0,0); LDFRAG(A01,0,1); LDFRAG(A10,1,0); LDFRAG(A11,1,1);
        LDFRAG(A20,2,0); LDFRAG(A21,2,1); LDFRAG(A30,3,0); LDFRAG(A31,3,1);
        #undef LDFRAG
    }

    // ---- phase 3: ballot-pack y into LDS words ----
    unsigned long long* yball = (unsigned long long*)(SM + OFF_YB);
    #pragma unroll
    for (int q = 0; q < 8; q++) {
        const int row = wv*8 + q;
        const int* yr = y + (size_t)(R0 + row) * TLEN;
        #pragma unroll
        for (int w = 0; w < 16; w++) {
            const unsigned long long bal = __ballot(yr[w*64 + lane] != 0);
            if (lane == 0) yball[row*16 + w] = bal;
        }
    }
    __syncthreads();

    // ---- phase 4: per-lane bit-streams -> per-lane LDS slots ----
    // stream bit s: fwd -> y[s+1] (s=0..510); bwd -> y[1022-s]
    unsigned long long* ybsL = (unsigned long long*)(SM + OFF_YS) + wv*(8*64);
    int initbit;
    {
        unsigned long long raw[8];
        if (wv == 0) {
            #pragma unroll
            for (int w = 0; w < 8; w++) raw[w] = yball[lr*16 + w];
        } else {
            #pragma unroll
            for (int w = 0; w < 8; w++) raw[w] = __brevll(yball[lr*16 + (15-w)]);
        }
        initbit = (int)(raw[0] & 1ull);           // fwd: y[0]; bwd: y[1023]
        #pragma unroll
        for (int w = 0; w < 7; w++)
            ybsL[w*64 + lane] = (raw[w] >> 1) | (raw[w+1] << 63);
        ybsL[7*64 + lane] = raw[7] >> 1;
    }
    // Each lane reads back ONLY its own ybsL slots (same-wave write->read).

    // ---- e pairs: e0 and ed = e1 - e0, 8 f32x2 each ----
    const f32x2 e0p0 = *(const f32x2*)(pE +  0 + 4*g);
    const f32x2 e0p1 = *(const f32x2*)(pE +  2 + 4*g);
    const f32x2 e0p2 = *(const f32x2*)(pE + 16 + 4*g);
    const f32x2 e0p3 = *(const f32x2*)(pE + 18 + 4*g);
    const f32x2 e0p4 = *(const f32x2*)(pE + 32 + 4*g);
    const f32x2 e0p5 = *(const f32x2*)(pE + 34 + 4*g);
    const f32x2 e0p6 = *(const f32x2*)(pE + 48 + 4*g);
    const f32x2 e0p7 = *(const f32x2*)(pE + 50 + 4*g);
    const f32x2 ed0 = *(const f32x2*)(pE + 64 +  0 + 4*g) - e0p0;
    const f32x2 ed1 = *(const f32x2*)(pE + 64 +  2 + 4*g) - e0p1;
    const f32x2 ed2 = *(const f32x2*)(pE + 64 + 16 + 4*g) - e0p2;
    const f32x2 ed3 = *(const f32x2*)(pE + 64 + 18 + 4*g) - e0p3;
    const f32x2 ed4 = *(const f32x2*)(pE + 64 + 32 + 4*g) - e0p4;
    const f32x2 ed5 = *(const f32x2*)(pE + 64 + 34 + 4*g) - e0p5;
    const f32x2 ed6 = *(const f32x2*)(pE + 64 + 48 + 4*g) - e0p6;
    const f32x2 ed7 = *(const f32x2*)(pE + 64 + 50 + 4*g) - e0p7;

    // ---- init chain state as 8 f32x2 pairs ----
    f32x2 dp0,dp1,dp2,dp3,dp4,dp5,dp6,dp7;
    {
        const float bvi_ = initbit ? 1.0f : 0.0f;
        const f32x2 bv = {bvi_, bvi_};
        const f32x2 es0 = pk_fma(bv, ed0, e0p0);
        const f32x2 es1 = pk_fma(bv, ed1, e0p1);
        const f32x2 es2 = pk_fma(bv, ed2, e0p2);
        const f32x2 es3 = pk_fma(bv, ed3, e0p3);
        const f32x2 es4 = pk_fma(bv, ed4, e0p4);
        const f32x2 es5 = pk_fma(bv, ed5, e0p5);
        const f32x2 es6 = pk_fma(bv, ed6, e0p6);
        const f32x2 es7 = pk_fma(bv, ed7, e0p7);
        if (wv == 0) {                    // alpha_0 = piv ⊙ e_{y0}
            dp0 = *(const f32x2*)(piv +  0 + 4*g) * es0;
            dp1 = *(const f32x2*)(piv +  2 + 4*g) * es1;
            dp2 = *(const f32x2*)(piv + 16 + 4*g) * es2;
            dp3 = *(const f32x2*)(piv + 18 + 4*g) * es3;
            dp4 = *(const f32x2*)(piv + 32 + 4*g) * es4;
            dp5 = *(const f32x2*)(piv + 34 + 4*g) * es5;
            dp6 = *(const f32x2*)(piv + 48 + 4*g) * es6;
            dp7 = *(const f32x2*)(piv + 50 + 4*g) * es7;
        } else {                          // gamma_1023 = e_{y1023}
            dp0 = es0; dp1 = es1; dp2 = es2; dp3 = es3;
            dp4 = es4; dp5 = es5; dp6 = es6; dp7 = es7;
        }
    }

    // ---- main loop: 511 register-only steps ----
    f32x4 t0, t1, t2, t3;
    #define DO_MM() { \
        u32x4 w1_, w2_; \
        w1_[0] = packpair(dp0.x, dp0.y);  w1_[1] = packpair(dp1.x, dp1.y); \
        w1_[2] = packpair(dp2.x, dp2.y);  w1_[3] = packpair(dp3.x, dp3.y); \
        w2_[0] = packpair(dp4.x, dp4.y);  w2_[1] = packpair(dp5.x, dp5.y); \
        w2_[2] = packpair(dp6.x, dp6.y);  w2_[3] = packpair(dp7.x, dp7.y); \
        const bf16x8 b1 = __builtin_bit_cast(bf16x8, w1_); \
        const bf16x8 b2 = __builtin_bit_cast(bf16x8, w2_); \
        t0 = MFMA(A00, b1, zero); t1 = MFMA(A10, b1, zero); \
        t2 = MFMA(A20, b1, zero); t3 = MFMA(A30, b1, zero); \
        t0 = MFMA(A01, b2, t0);   t1 = MFMA(A11, b2, t1); \
        t2 = MFMA(A21, b2, t2);   t3 = MFMA(A31, b2, t3); \
    }
    #define EMIT_BIT(cond) { \
        const float bf_ = (cond) ? 1.0f : 0.0f; \
        const f32x2 bv_ = {bf_, bf_}; \
        dp0 = pk_mul(lo2(t0), pk_fma(bv_, ed0, e0p0)); \
        dp1 = pk_mul(hi2(t0), pk_fma(bv_, ed1, e0p1)); \
        dp2 = pk_mul(lo2(t1), pk_fma(bv_, ed2, e0p2)); \
        dp3 = pk_mul(hi2(t1), pk_fma(bv_, ed3, e0p3)); \
        dp4 = pk_mul(lo2(t2), pk_fma(bv_, ed4, e0p4)); \
        dp5 = pk_mul(hi2(t2), pk_fma(bv_, ed5, e0p5)); \
        dp6 = pk_mul(lo2(t3), pk_fma(bv_, ed6, e0p6)); \
        dp7 = pk_mul(hi2(t3), pk_fma(bv_, ed7, e0p7)); \
    }

    float lacc = 0.f;
    // 31 groups x 16 steps = steps 0..495; renorm at step 15 of each group.
    #pragma unroll 1
    for (int grp = 0; grp < 31; ++grp) {
        const unsigned long long cw = ybsL[((grp >> 2) << 6) + lane];
        const u32 bits = (u32)(cw >> ((grp & 3) << 4));
        #pragma unroll
        for (int i = 0; i < 16; ++i) {
            DO_MM();
            if (i == 15) {                      // renorm every 16 steps
                float S = t0.x+t0.y+t0.z+t0.w + t1.x+t1.y+t1.z+t1.w
                        + t2.x+t2.y+t2.z+t2.w + t3.x+t3.y+t3.z+t3.w;
                S += __shfl_xor(S, 16);
                S += __shfl_xor(S, 32);
                lacc += __logf(S);
                const float rn = __builtin_amdgcn_rcpf(S);
                t0 *= rn; t1 *= rn; t2 *= rn; t3 *= rn;
            }
            EMIT_BIT(((bits >> i) & 1u) != 0u);
        }
    }
    // tail: steps 496..510 (stream bits 48..62 of word 7), rolled
    {
        u32 bits = (u32)(ybsL[(7 << 6) + lane] >> 48);
        #pragma unroll 1
        for (int i = 0; i < 15; ++i) {
            DO_MM();
            EMIT_BIT((bits & 1u) != 0u);
            bits >>= 1;
        }
    }

    // ---- fwd: one bare matvec (no emission) -> abar_512 ----
    if (wv == 0) {
        DO_MM();
        dp0 = lo2(t0); dp1 = hi2(t0); dp2 = lo2(t1); dp3 = hi2(t1);
        dp4 = lo2(t2); dp5 = hi2(t2); dp6 = lo2(t3); dp7 = hi2(t3);
    }
    #undef DO_MM
    #undef EMIT_BIT

    // reconstruct f32x4 view for the combine
    const f32x4 d0 = {dp0.x, dp0.y, dp1.x, dp1.y};
    const f32x4 d1 = {dp2.x, dp2.y, dp3.x, dp3.y};
    const f32x4 d2 = {dp4.x, dp4.y, dp5.x, dp5.y};
    const f32x4 d3 = {dp6.x, dp6.y, dp7.x, dp7.y};

    // ---- combine: logP = laccF + laccB + log(abar_512 . gamma_512) ----
    if (wv == 1) {
        float* CB = (float*)(SM + OFF_CMB);
        *(f32x4*)(CB + lr*CSTR +  0 + 4*g) = d0;
        *(f32x4*)(CB + lr*CSTR + 16 + 4*g) = d1;
        *(f32x4*)(CB + lr*CSTR + 32 + 4*g) = d2;
        *(f32x4*)(CB + lr*CSTR + 48 + 4*g) = d3;
        if (lane < 16) ((float*)(SM + OFF_LACB))[lane] = lacc;
    }
    __syncthreads();
    if (wv == 0) {
        const float* CB = (const float*)(SM + OFF_CMB);
        const f32x4 q0 = *(const f32x4*)(CB + lr*CSTR +  0 + 4*g);
        const f32x4 q1 = *(const f32x4*)(CB + lr*CSTR + 16 + 4*g);
        const f32x4 q2 = *(const f32x4*)(CB + lr*CSTR + 32 + 4*g);
        const f32x4 q3 = *(const f32x4*)(CB + lr*CSTR + 48 + 4*g);
        float dot = d0.x*q0.x + d0.y*q0.y + d0.z*q0.z + d0.w*q0.w
                  + d1.x*q1.x + d1.y*q1.y + d1.z*q1.z + d1.w*q1.w
                  + d2.x*q2.x + d2.y*q2.y + d2.z*q2.z + d2.w*q2.w
                  + d3.x*q3.x + d3.y*q3.y + d3.z*q3.z + d3.w*q3.w;
        dot += __shfl_xor(dot, 16);
        dot += __shfl_xor(dot, 32);
        float lp = lacc + ((const float*)(SM + OFF_LACB))[lr] + __logf(dot);
        if (g == 0) {                      // lanes 0..15: reduce over batch
            lp += __shfl_xor(lp, 1);
            lp += __shfl_xor(lp, 2);
            lp += __shfl_xor(lp, 4);
            lp += __shfl_xor(lp, 8);
            if (lr == 0) atomicAdd(out, lp * (1.0f / BATCH));
        }
    }
}

// ---------------------------------------------------------------------------
extern "C" void kernel_launch(void* const* d_in, const int* in_sizes, int n_in,
                              void* d_out, int out_size, void* d_ws, size_t ws_size,
                              hipStream_t stream) {
    const int*   y  = (const int*)  d_in[0];
    const float* T  = (const float*)d_in[1];
    const float* E  = (const float*)d_in[2];
    const float* Pi = (const float*)d_in[3];
    float* out = (float*)d_out;
    (void)d_ws; (void)ws_size; (void)in_sizes; (void)n_in; (void)out_size;

    hipMemsetAsync(out, 0, sizeof(float), stream);
    hipLaunchKernelGGL(hmm_fb, dim3(BATCH/16), dim3(128), 0, stream,
                       y, T, E, Pi, out);
}

// Round 14
// 172.238 us; speedup vs baseline: 1.1925x; 1.0181x over previous
//
#include <hip/hip_runtime.h>
#include <hip/hip_bf16.h>
#include <stdint.h>

#define BATCH 4096
#define TLEN  1024
#define MSTR  72     // LDS stride (bf16 elems) for T matrices; 144B keeps b64/b128 alignment
#define CSTR  68     // combine buffer stride (f32); 272B keeps f32x4 alignment

// ---- LDS layout (bytes) ----
#define OFF_T    0        // Tsm plain [64][MSTR] bf16   (bwd A source)
#define OFF_G    9216     // Tsm^T     [64][MSTR] bf16   (fwd A source)
#define OFF_PE   18432    // float pE[2][64]
#define OFF_PIV  18944    // float piv[64]
#define OFF_YB   19200    // u64 yball[16][16] = 2048
#define OFF_CMB  21376    // float gamma[16][CSTR]
#define OFF_LACB 25728    // float laccB[16]
#define OFF_YS   25792    // u64 ybsL[2 waves][8 words][64 lanes] = 8192
#define SMEM_SZ  33984

typedef short        bf16x4 __attribute__((ext_vector_type(4)));
typedef short        bf16x8 __attribute__((ext_vector_type(8)));
typedef float        f32x4  __attribute__((ext_vector_type(4)));
typedef unsigned int u32;
typedef unsigned int u32x4  __attribute__((ext_vector_type(4)));

#define MFMA(a,b,c) __builtin_amdgcn_mfma_f32_16x16x32_bf16(a,b,c,0,0,0)

// Hardware packed f32->2xbf16 (RNE). One VALU op replaces ~6 of software RNE.
static __device__ __forceinline__ u32 packpair(float lo, float hi) {
    u32 r;
    asm("v_cvt_pk_bf16_f32 %0, %1, %2" : "=&v"(r) : "v"(lo), "v"(hi));
    return r;
}

// ---------------------------------------------------------------------------
// FINAL STRUCTURE (= round 7, the measured optimum of 13 variants).
// 256 wgs x 128 thr (2 waves). wg = 16-batch block, BOTH directions:
//   wave0: forward  alpha-chain, A = T^T (permuted k-order)
//   wave1: backward gamma-chain (gamma_t = e_t ⊙ beta_t), A = T (permuted)
// Register-only chain: MFMA D-fragment (rows = states m*16+4g+r, col = lr)
// is repacked directly as next step's B-fragment via the k-slot permutation
// sigma(h,g,j) = 32h + 4g + (j&3) + 16*(j>>2) applied to the A-gather.
// Main loop is code-size-bounded: '#pragma unroll 1' outer loop over 31
// 16-step unrolled groups (fits L1I) + rolled 15-step tail; per-lane LDS
// bit-words. Renorm every 16 steps. Combine in-wg; no workspace.
//
// Measured floor ledger (r6-r13): time = wave-issue-cycles x ~4.5
// (lone-wave dependent-stall factor). Structural alternatives all at or
// above this: 2-chain ILP in-wave = exactly 2x (r9/r10), split-K = +27%
// (r12), exec-mask EMIT = +13% (r11), packed-fp32 EMIT = 0 (r13, VOP3P
// costs 2x issue), A-side emission fold = +23% (r8), pair-step = +75%
// (r5). Parallelism is structurally capped at 512 waves (4096/16 cols x 2
// directions) on 1024 SIMDs; per-column VALU work is width-invariant.
// Floor: 511 serial steps x ~580 cy ~= 123 us dispatch.
// ---------------------------------------------------------------------------
__global__ __launch_bounds__(128, 1) void hmm_fb(
    const int* __restrict__ y, const float* __restrict__ Tmat,
    const float* __restrict__ Emat, const float* __restrict__ Pi,
    float* __restrict__ out)
{
    __shared__ __align__(16) unsigned char SM[SMEM_SZ];

    const int tid  = threadIdx.x;
    const int wv   = tid >> 6;          // 0 = fwd, 1 = bwd
    const int lane = tid & 63;
    const int lr   = lane & 15;         // batch col
    const int g    = lane >> 4;         // k-group
    const int R0   = blockIdx.x << 4;

    float* pE  = (float*)(SM + OFF_PE);
    float* piv = (float*)(SM + OFF_PIV);
    const f32x4 zero = {0.f, 0.f, 0.f, 0.f};

    // ---- phase 0: emission + pi softmax ----
    if (tid < 64) {
        const float e0 = Emat[tid*2+0], e1 = Emat[tid*2+1];
        const float em = fmaxf(e0, e1);
        const float p0 = __expf(e0-em), p1 = __expf(e1-em);
        const float ez = 1.0f / (p0 + p1);
        pE[tid]      = p0 * ez;
        pE[64 + tid] = p1 * ez;
        float v = Pi[tid];
        float mx = v;
        #pragma unroll
        for (int d = 1; d < 64; d <<= 1) mx = fmaxf(mx, __shfl_xor(mx, d));
        const float e = __expf(v - mx);
        float z = e;
        #pragma unroll
        for (int d = 1; d < 64; d <<= 1) z += __shfl_xor(z, d);
        piv[tid] = e / z;
    }

    // ---- phase 1: row-softmax of T -> plain + transposed bf16 ----
    {
        const int r  = tid >> 1;          // 0..63
        const int hh = tid & 1;           // 32-col half
        float v[32];
        #pragma unroll
        for (int q = 0; q < 8; q++) {
            const float4 t4 = *(const float4*)(Tmat + r*64 + hh*32 + q*4);
            v[q*4+0]=t4.x; v[q*4+1]=t4.y; v[q*4+2]=t4.z; v[q*4+3]=t4.w;
        }
        float mx = v[0];
        #pragma unroll
        for (int k = 1; k < 32; k++) mx = fmaxf(mx, v[k]);
        mx = fmaxf(mx, __shfl_xor(mx, 1));
        float z = 0.f;
        #pragma unroll
        for (int k = 0; k < 32; k++) { v[k] = __expf(v[k]-mx); z += v[k]; }
        z += __shfl_xor(z, 1);
        const float inv = 1.0f / z;
        __hip_bfloat16* Tsm = (__hip_bfloat16*)(SM + OFF_T);
        __hip_bfloat16* Gt  = (__hip_bfloat16*)(SM + OFF_G);
        #pragma unroll
        for (int k = 0; k < 32; k++) {
            const int j = hh*32 + k;
            const __hip_bfloat16 hb = __float2bfloat16(v[k] * inv);
            Tsm[r*MSTR + j] = hb;     // Tsm[s][s']
            Gt[j*MSTR + r]  = hb;     // Gt[s'][s] = T[s][s']
        }
    }
    __syncthreads();

    // ---- phase 2: gather permuted A-fragments (register-resident) ----
    // A[m][h] element j (lane g): col sigma = 32h + 4g + (j&3) + 16*(j>>2)
    bf16x8 A00,A01,A10,A11,A20,A21,A30,A31;
    {
        const __hip_bfloat16* Abase =
            (const __hip_bfloat16*)(SM + (wv == 0 ? OFF_G : OFF_T));
        #define LDFRAG(dst, m, h) { \
            const __hip_bfloat16* p_ = Abase + ((m)*16+lr)*MSTR + 32*(h) + 4*g; \
            bf16x4 lo_ = *(const bf16x4*)(p_); \
            bf16x4 hi_ = *(const bf16x4*)(p_ + 16); \
            dst[0]=lo_[0]; dst[1]=lo_[1]; dst[2]=lo_[2]; dst[3]=lo_[3]; \
            dst[4]=hi_[0]; dst[5]=hi_[1]; dst[6]=hi_[2]; dst[7]=hi_[3]; \
        }
        LDFRAG(A00,0,0); LDFRAG(A01,0,1); LDFRAG(A10,1,0); LDFRAG(A11,1,1);
        LDFRAG(A20,2,0); LDFRAG(A21,2,1); LDFRAG(A30,3,0); LDFRAG(A31,3,1);
        #undef LDFRAG
    }

    // ---- phase 3: ballot-pack y into LDS words ----
    unsigned long long* yball = (unsigned long long*)(SM + OFF_YB);
    #pragma unroll
    for (int q = 0; q < 8; q++) {
        const int row = wv*8 + q;
        const int* yr = y + (size_t)(R0 + row) * TLEN;
        #pragma unroll
        for (int w = 0; w < 16; w++) {
            const unsigned long long bal = __ballot(yr[w*64 + lane] != 0);
            if (lane == 0) yball[row*16 + w] = bal;
        }
    }
    __syncthreads();

    // ---- phase 4: per-lane bit-streams -> per-lane LDS slots ----
    // stream bit s: fwd -> y[s+1] (s=0..510); bwd -> y[1022-s]
    unsigned long long* ybsL = (unsigned long long*)(SM + OFF_YS) + wv*(8*64);
    int initbit;
    {
        unsigned long long raw[8];
        if (wv == 0) {
            #pragma unroll
            for (int w = 0; w < 8; w++) raw[w] = yball[lr*16 + w];
        } else {
            #pragma unroll
            for (int w = 0; w < 8; w++) raw[w] = __brevll(yball[lr*16 + (15-w)]);
        }
        initbit = (int)(raw[0] & 1ull);           // fwd: y[0]; bwd: y[1023]
        #pragma unroll
        for (int w = 0; w < 7; w++)
            ybsL[w*64 + lane] = (raw[w] >> 1) | (raw[w+1] << 63);
        ybsL[7*64 + lane] = raw[7] >> 1;
    }
    // Each lane reads back ONLY its own ybsL slots (same-wave write->read).

    const f32x4 e0_0 = *(const f32x4*)(pE +       0 + 4*g);
    const f32x4 e0_1 = *(const f32x4*)(pE +      16 + 4*g);
    const f32x4 e0_2 = *(const f32x4*)(pE +      32 + 4*g);
    const f32x4 e0_3 = *(const f32x4*)(pE +      48 + 4*g);
    const f32x4 e1_0 = *(const f32x4*)(pE + 64 +  0 + 4*g);
    const f32x4 e1_1 = *(const f32x4*)(pE + 64 + 16 + 4*g);
    const f32x4 e1_2 = *(const f32x4*)(pE + 64 + 32 + 4*g);
    const f32x4 e1_3 = *(const f32x4*)(pE + 64 + 48 + 4*g);

    f32x4 d0, d1, d2, d3;
    if (wv == 0) {                        // alpha_0 = piv ⊙ e_{y0}
        const f32x4 p0 = *(const f32x4*)(piv +  0 + 4*g);
        const f32x4 p1 = *(const f32x4*)(piv + 16 + 4*g);
        const f32x4 p2 = *(const f32x4*)(piv + 32 + 4*g);
        const f32x4 p3 = *(const f32x4*)(piv + 48 + 4*g);
        d0 = p0 * (initbit ? e1_0 : e0_0);
        d1 = p1 * (initbit ? e1_1 : e0_1);
        d2 = p2 * (initbit ? e1_2 : e0_2);
        d3 = p3 * (initbit ? e1_3 : e0_3);
    } else {                              // gamma_1023 = e_{y1023}
        d0 = initbit ? e1_0 : e0_0;
        d1 = initbit ? e1_1 : e0_1;
        d2 = initbit ? e1_2 : e0_2;
        d3 = initbit ? e1_3 : e0_3;
    }

    // ---- main loop: 511 register-only steps, code-size-bounded ----
    f32x4 t0, t1, t2, t3;
    #define DO_MM() { \
        u32x4 w1_, w2_; \
        w1_[0] = packpair(d0.x, d0.y);  w1_[1] = packpair(d0.z, d0.w); \
        w1_[2] = packpair(d1.x, d1.y);  w1_[3] = packpair(d1.z, d1.w); \
        w2_[0] = packpair(d2.x, d2.y);  w2_[1] = packpair(d2.z, d2.w); \
        w2_[2] = packpair(d3.x, d3.y);  w2_[3] = packpair(d3.z, d3.w); \
        const bf16x8 b1 = __builtin_bit_cast(bf16x8, w1_); \
        const bf16x8 b2 = __builtin_bit_cast(bf16x8, w2_); \
        t0 = MFMA(A00, b1, zero); t1 = MFMA(A10, b1, zero); \
        t2 = MFMA(A20, b1, zero); t3 = MFMA(A30, b1, zero); \
        t0 = MFMA(A01, b2, t0);   t1 = MFMA(A11, b2, t1); \
        t2 = MFMA(A21, b2, t2);   t3 = MFMA(A31, b2, t3); \
    }
    #define EMIT_BIT(cond) { \
        const bool yb_ = (cond); \
        d0 = t0 * (yb_ ? e1_0 : e0_0); \
        d1 = t1 * (yb_ ? e1_1 : e0_1); \
        d2 = t2 * (yb_ ? e1_2 : e0_2); \
        d3 = t3 * (yb_ ? e1_3 : e0_3); \
    }

    float lacc = 0.f;
    // 31 groups x 16 steps = steps 0..495; renorm at step 15 of each group.
    #pragma unroll 1
    for (int grp = 0; grp < 31; ++grp) {
        const unsigned long long cw = ybsL[((grp >> 2) << 6) + lane];
        const u32 bits = (u32)(cw >> ((grp & 3) << 4));
        #pragma unroll
        for (int i = 0; i < 16; ++i) {
            DO_MM();
            if (i == 15) {                      // renorm every 16 steps
                float S = t0.x+t0.y+t0.z+t0.w + t1.x+t1.y+t1.z+t1.w
                        + t2.x+t2.y+t2.z+t2.w + t3.x+t3.y+t3.z+t3.w;
                S += __shfl_xor(S, 16);
                S += __shfl_xor(S, 32);
                lacc += __logf(S);
                const float rn = __builtin_amdgcn_rcpf(S);
                t0 *= rn; t1 *= rn; t2 *= rn; t3 *= rn;
            }
            EMIT_BIT(((bits >> i) & 1u) != 0u);
        }
    }
    // tail: steps 496..510 (stream bits 48..62 of word 7), rolled
    {
        u32 bits = (u32)(ybsL[(7 << 6) + lane] >> 48);
        #pragma unroll 1
        for (int i = 0; i < 15; ++i) {
            DO_MM();
            EMIT_BIT((bits & 1u) != 0u);
            bits >>= 1;
        }
    }

    // ---- fwd: one bare matvec (no emission) -> abar_512 ----
    if (wv == 0) {
        DO_MM();
        d0 = t0; d1 = t1; d2 = t2; d3 = t3;
    }
    #undef DO_MM
    #undef EMIT_BIT

    // ---- combine: logP = laccF + laccB + log(abar_512 . gamma_512) ----
    if (wv == 1) {
        float* CB = (float*)(SM + OFF_CMB);
        *(f32x4*)(CB + lr*CSTR +  0 + 4*g) = d0;
        *(f32x4*)(CB + lr*CSTR + 16 + 4*g) = d1;
        *(f32x4*)(CB + lr*CSTR + 32 + 4*g) = d2;
        *(f32x4*)(CB + lr*CSTR + 48 + 4*g) = d3;
        if (lane < 16) ((float*)(SM + OFF_LACB))[lane] = lacc;
    }
    __syncthreads();
    if (wv == 0) {
        const float* CB = (const float*)(SM + OFF_CMB);
        const f32x4 q0 = *(const f32x4*)(CB + lr*CSTR +  0 + 4*g);
        const f32x4 q1 = *(const f32x4*)(CB + lr*CSTR + 16 + 4*g);
        const f32x4 q2 = *(const f32x4*)(CB + lr*CSTR + 32 + 4*g);
        const f32x4 q3 = *(const f32x4*)(CB + lr*CSTR + 48 + 4*g);
        float dot = d0.x*q0.x + d0.y*q0.y + d0.z*q0.z + d0.w*q0.w
                  + d1.x*q1.x + d1.y*q1.y + d1.z*q1.z + d1.w*q1.w
                  + d2.x*q2.x + d2.y*q2.y + d2.z*q2.z + d2.w*q2.w
                  + d3.x*q3.x + d3.y*q3.y + d3.z*q3.z + d3.w*q3.w;
        dot += __shfl_xor(dot, 16);
        dot += __shfl_xor(dot, 32);
        float lp = lacc + ((const float*)(SM + OFF_LACB))[lr] + __logf(dot);
        if (g == 0) {                      // lanes 0..15: reduce over batch
            lp += __shfl_xor(lp, 1);
            lp += __shfl_xor(lp, 2);
            lp += __shfl_xor(lp, 4);
            lp += __shfl_xor(lp, 8);
            if (lr == 0) atomicAdd(out, lp * (1.0f / BATCH));
        }
    }
}

// ---------------------------------------------------------------------------
extern "C" void kernel_launch(void* const* d_in, const int* in_sizes, int n_in,
                              void* d_out, int out_size, void* d_ws, size_t ws_size,
                              hipStream_t stream) {
    const int*   y  = (const int*)  d_in[0];
    const float* T  = (const float*)d_in[1];
    const float* E  = (const float*)d_in[2];
    const float* Pi = (const float*)d_in[3];
    float* out = (float*)d_out;
    (void)d_ws; (void)ws_size; (void)in_sizes; (void)n_in; (void)out_size;

    hipMemsetAsync(out, 0, sizeof(float), stream);
    hipLaunchKernelGGL(hmm_fb, dim3(BATCH/16), dim3(128), 0, stream,
                       y, T, E, Pi, out);
}